// Round 1
// baseline (176.362 us; speedup 1.0000x reference)
//
#include <hip/hip_runtime.h>
#include <math.h>

// Problem constants (from reference): LMAX=8, BVALS={1,2,3}
#define FF 3          // fibers per voxel
#define BB 3          // b-values
#define KK 45         // SH terms for even l in [0,8]: 1+5+9+13+17
#define WAVES 9       // FF*BB waves per block
#define TPB (WAVES*64)

// map k in [0,45) -> (l, m, lidx)
__device__ __forceinline__ void k_to_lm(int k, int& l, int& m, int& lidx) {
    int base;
    if (k < 1)       { l = 0; base = 0;  lidx = 0; }
    else if (k < 6)  { l = 2; base = 1;  lidx = 1; }
    else if (k < 15) { l = 4; base = 6;  lidx = 2; }
    else if (k < 28) { l = 6; base = 15; lidx = 3; }
    else             { l = 8; base = 28; lidx = 4; }
    m = k - base - l;
}

__global__ __launch_bounds__(TPB) void fused_sim_kernel(
    const float* __restrict__ directs,   // (N,F,3)
    const float* __restrict__ weights,   // (N,F)
    const float* __restrict__ shapes,    // (N,F,4): D_a, D_epar, D_eperp, z
    const int*   __restrict__ num_t_p,   // scalar
    float* __restrict__ outS,            // (N,B,K)
    float* __restrict__ outODF,          // (N,F,K)
    float* __restrict__ outEig)          // (N,B,F,K)
{
    const int n    = blockIdx.x;
    const int tid  = threadIdx.x;
    const int lane = tid & 63;
    const int w    = tid >> 6;          // wave id 0..8
    const int T    = num_t_p[0];

    __shared__ float rho_s[WAVES * 5];  // [f*3+b][lidx]
    __shared__ float sh_s[FF * KK];     // ODF basis per fiber

    // ---------------- Phase 1a: SH basis (threads 0..134) ----------------
    if (tid < FF * KK) {
        const int f = tid / KK;
        const int k = tid % KK;
        const float dx = directs[(n * FF + f) * 3 + 0];
        const float dy = directs[(n * FF + f) * 3 + 1];
        const float dz = directs[(n * FF + f) * 3 + 2];
        const float inv = 1.0f / sqrtf(dx * dx + dy * dy + dz * dz);
        const float x = dx * inv, y = dy * inv, z = dz * inv;
        const float phi = atan2f(y, x);
        float s2 = 1.0f - z * z;
        s2 = fminf(fmaxf(s2, 0.0f), 1.0f);
        const float s = sqrtf(s2);

        int l, m, lidx;
        k_to_lm(k, l, m, lidx);
        const int ma = (m < 0) ? -m : m;

        // associated Legendre P(l, ma) at z (Condon-Shortley)
        float pmm = 1.0f;
        for (int mm = 1; mm <= ma; ++mm)
            pmm *= -(float)(2 * mm - 1) * s;
        float P;
        if (l == ma) {
            P = pmm;
        } else {
            float pa = pmm;                              // P(ma,ma)
            float pb = (float)(2 * ma + 1) * z * pa;     // P(ma+1,ma)
            for (int ll = ma + 2; ll <= l; ++ll) {
                float pn = ((float)(2 * ll - 1) * z * pb - (float)(ll + ma - 1) * pa)
                           / (float)(ll - ma);
                pa = pb; pb = pn;
            }
            P = pb;
        }

        // normalization: sqrt((2l+1)/(4pi) * (l-ma)!/(l+ma)!)
        float ratio = 1.0f;
        for (int i = l - ma + 1; i <= l + ma; ++i) ratio /= (float)i;
        float nrm = sqrtf((float)(2 * l + 1) * 0.079577471545947668f * ratio);

        float val;
        if (m < 0)       val = 1.4142135623730951f * nrm * sinf((float)ma * phi) * P;
        else if (m == 0) val = nrm * P;
        else             val = 1.4142135623730951f * nrm * cosf((float)m * phi) * P;

        sh_s[f * KK + k] = val;
        outODF[(size_t)(n * FF + f) * KK + k] = val;
    }

    // ---------------- Phase 1b: rho per (f,b) wave ----------------
    {
        const int f  = w / BB;
        const int bi = w % BB;
        const float bval = (float)(bi + 1);              // BVALS = {1,2,3}

        const float D_a     = shapes[(n * FF + f) * 4 + 0];
        const float D_epar  = shapes[(n * FF + f) * 4 + 1];
        const float D_eperp = shapes[(n * FF + f) * 4 + 2];
        const float zf      = shapes[(n * FF + f) * 4 + 3];

        const float bA = bval * D_a;
        const float bE = bval * (D_epar - D_eperp);
        const float zc = (1.0f - zf) * __expf(-bval * D_eperp);

        const float inv_tm1 = 1.0f / (float)(T - 1);
        const float wbase   = 1.0f / (float)T;

        float a0 = 0.f, a1 = 0.f, a2 = 0.f, a3 = 0.f, a4 = 0.f;
        for (int i = lane; i < T; i += 64) {
            const float t  = (float)i * inv_tm1;
            const float t2 = t * t;
            const float e1 = __expf(-bA * t2);
            const float e2 = __expf(-bE * t2);
            const float kv = zf * e1 + zc * e2;
            const float wi = (i == 0 || i == T - 1) ? 0.5f * wbase : wbase;
            const float kw = kv * wi;

            // even Legendre P2,P4,P6,P8 via recurrence
            const float p0 = 1.0f, p1 = t;
            const float p2 = 1.5f * t * p1 - 0.5f * p0;
            const float p3 = (5.0f / 3.0f) * t * p2 - (2.0f / 3.0f) * p1;
            const float p4 = 1.75f * t * p3 - 0.75f * p2;
            const float p5 = 1.8f * t * p4 - 0.8f * p3;
            const float p6 = (11.0f / 6.0f) * t * p5 - (5.0f / 6.0f) * p4;
            const float p7 = (13.0f / 7.0f) * t * p6 - (6.0f / 7.0f) * p5;
            const float p8 = 1.875f * t * p7 - 0.875f * p6;

            a0 += kw;
            a1 = fmaf(kw, p2, a1);
            a2 = fmaf(kw, p4, a2);
            a3 = fmaf(kw, p6, a3);
            a4 = fmaf(kw, p8, a4);
        }

        // wave-wide butterfly reduction (64 lanes)
        for (int off = 1; off < 64; off <<= 1) {
            a0 += __shfl_xor(a0, off);
            a1 += __shfl_xor(a1, off);
            a2 += __shfl_xor(a2, off);
            a3 += __shfl_xor(a3, off);
            a4 += __shfl_xor(a4, off);
        }
        if (lane == 0) {
            rho_s[w * 5 + 0] = a0;
            rho_s[w * 5 + 1] = a1;
            rho_s[w * 5 + 2] = a2;
            rho_s[w * 5 + 3] = a3;
            rho_s[w * 5 + 4] = a4;
        }
    }

    __syncthreads();

    // ---------------- Phase 2a: eigen_values (N,B,F,K) ----------------
    if (tid < BB * FF * KK) {          // 405 threads
        const int bi = tid / (FF * KK);
        const int r  = tid % (FF * KK);
        const int f  = r / KK;
        const int k  = r % KK;
        int l, m, lidx;
        k_to_lm(k, l, m, lidx);
        outEig[(size_t)((n * BB + bi) * FF + f) * KK + k] = rho_s[(f * BB + bi) * 5 + lidx];
    }

    // ---------------- Phase 2b: Stensor (N,B,K) ----------------
    if (tid < BB * KK) {               // 135 threads
        const int bi = tid / KK;
        const int k  = tid % KK;
        int l, m, lidx;
        k_to_lm(k, l, m, lidx);
        float ssum = 0.0f;
        #pragma unroll
        for (int f = 0; f < FF; ++f) {
            ssum += weights[n * FF + f] * rho_s[(f * BB + bi) * 5 + lidx] * sh_s[f * KK + k];
        }
        outS[(size_t)(n * BB + bi) * KK + k] = ssum;
    }
}

extern "C" void kernel_launch(void* const* d_in, const int* in_sizes, int n_in,
                              void* d_out, int out_size, void* d_ws, size_t ws_size,
                              hipStream_t stream) {
    const float* directs = (const float*)d_in[0];   // (N,F,3)
    const float* weights = (const float*)d_in[1];   // (N,F)
    const float* shapes  = (const float*)d_in[2];   // (N,F,4)
    const int*   num_t   = (const int*)d_in[3];     // scalar

    const int N = in_sizes[0] / (FF * 3);

    float* outS   = (float*)d_out;                        // N*BB*KK
    float* outODF = outS + (size_t)N * BB * KK;           // N*FF*KK
    float* outEig = outODF + (size_t)N * FF * KK;         // N*BB*FF*KK

    fused_sim_kernel<<<N, TPB, 0, stream>>>(directs, weights, shapes, num_t,
                                            outS, outODF, outEig);
}

// Round 2
// 158.964 us; speedup vs baseline: 1.1094x; 1.1094x over previous
//
#include <hip/hip_runtime.h>
#include <math.h>

// Problem constants (from reference): LMAX=8, BVALS={1,2,3}
#define FF 3          // fibers per voxel
#define BB 3          // b-values
#define KK 45         // SH terms for even l in [0,8]: 1+5+9+13+17
#define WAVES 9       // FF*BB waves per block
#define TPB (WAVES*64)

// map k in [0,45) -> (l, m, lidx)
__device__ __forceinline__ void k_to_lm(int k, int& l, int& m, int& lidx) {
    int base;
    if (k < 1)       { l = 0; base = 0;  lidx = 0; }
    else if (k < 6)  { l = 2; base = 1;  lidx = 1; }
    else if (k < 15) { l = 4; base = 6;  lidx = 2; }
    else if (k < 28) { l = 6; base = 15; lidx = 3; }
    else             { l = 8; base = 28; lidx = 4; }
    m = k - base - l;
}

__global__ __launch_bounds__(TPB) void fused_sim_kernel(
    const float* __restrict__ directs,   // (N,F,3)
    const float* __restrict__ weights,   // (N,F)
    const float* __restrict__ shapes,    // (N,F,4): D_a, D_epar, D_eperp, z
    const int*   __restrict__ num_t_p,   // scalar
    float* __restrict__ outS,            // (N,B,K)
    float* __restrict__ outODF,          // (N,F,K)
    float* __restrict__ outEig)          // (N,B,F,K)
{
    const int n    = blockIdx.x;
    const int tid  = threadIdx.x;
    const int lane = tid & 63;
    const int w    = tid >> 6;          // wave id 0..8
    const int T    = num_t_p[0];

    __shared__ float rho_s[WAVES * 5];  // [f*3+b][lidx]
    __shared__ float sh_s[FF * KK];     // ODF basis per fiber

    // ---------------- Phase 1a: SH basis (threads 0..134) ----------------
    if (tid < FF * KK) {
        const int f = tid / KK;
        const int k = tid % KK;
        const float dx = directs[(n * FF + f) * 3 + 0];
        const float dy = directs[(n * FF + f) * 3 + 1];
        const float dz = directs[(n * FF + f) * 3 + 2];
        const float inv = 1.0f / sqrtf(dx * dx + dy * dy + dz * dz);
        const float x = dx * inv, y = dy * inv, z = dz * inv;
        float s2 = 1.0f - z * z;
        s2 = fminf(fmaxf(s2, 0.0f), 1.0f);
        const float s = sqrtf(s2);

        // cos(phi), sin(phi) without atan2: phi = atan2(y, x)
        const float rxy2 = x * x + y * y;
        float cphi = 1.0f, sphi = 0.0f;
        if (rxy2 > 0.0f) {
            const float ir = 1.0f / sqrtf(rxy2);
            cphi = x * ir;
            sphi = y * ir;
        }

        int l, m, lidx;
        k_to_lm(k, l, m, lidx);
        const int ma = (m < 0) ? -m : m;

        // cos(ma*phi), sin(ma*phi) via complex-mul recurrence
        float cm = 1.0f, sm = 0.0f;
        for (int mm = 0; mm < ma; ++mm) {
            const float cn = cm * cphi - sm * sphi;
            const float sn = sm * cphi + cm * sphi;
            cm = cn; sm = sn;
        }

        // associated Legendre P(l, ma) at z (Condon-Shortley)
        float pmm = 1.0f;
        for (int mm = 1; mm <= ma; ++mm)
            pmm *= -(float)(2 * mm - 1) * s;
        float P;
        if (l == ma) {
            P = pmm;
        } else {
            float pa = pmm;                              // P(ma,ma)
            float pb = (float)(2 * ma + 1) * z * pa;     // P(ma+1,ma)
            for (int ll = ma + 2; ll <= l; ++ll) {
                float pn = ((float)(2 * ll - 1) * z * pb - (float)(ll + ma - 1) * pa)
                           / (float)(ll - ma);
                pa = pb; pb = pn;
            }
            P = pb;
        }

        // normalization: sqrt((2l+1)/(4pi) / prod_{i=l-ma+1..l+ma} i)
        float prod = 1.0f;
        for (int i = l - ma + 1; i <= l + ma; ++i) prod *= (float)i;
        const float nrm = sqrtf((float)(2 * l + 1) * 0.079577471545947668f / prod);

        float val;
        if (m < 0)       val = 1.4142135623730951f * nrm * sm * P;
        else if (m == 0) val = nrm * P;
        else             val = 1.4142135623730951f * nrm * cm * P;

        sh_s[f * KK + k] = val;
        outODF[(size_t)(n * FF + f) * KK + k] = val;
    }

    // ---------------- Phase 1b: rho per (f,b) wave ----------------
    {
        const int f  = w / BB;
        const int bi = w % BB;
        const float bval = (float)(bi + 1);              // BVALS = {1,2,3}

        const float D_a     = shapes[(n * FF + f) * 4 + 0];
        const float D_epar  = shapes[(n * FF + f) * 4 + 1];
        const float D_eperp = shapes[(n * FF + f) * 4 + 2];
        const float zf      = shapes[(n * FF + f) * 4 + 3];

        const float bA = bval * D_a;
        const float bE = bval * (D_epar - D_eperp);
        const float zc = (1.0f - zf) * __expf(-bval * D_eperp);

        const float sstep = 1.0f / (float)(T - 1);       // dt
        const float a1 = bA * sstep * sstep;             // exp(-a1 * i^2)
        const float a2 = bE * sstep * sstep;
        const float fl = (float)lane;

        // geometric recurrences for exp(-a * (lane + 64k)^2)
        float e1 = zf * __expf(-a1 * fl * fl);
        float h1 = __expf(-a1 * (128.0f * fl + 4096.0f));
        const float c1 = __expf(-8192.0f * a1);
        float e2 = zc * __expf(-a2 * fl * fl);
        float h2 = __expf(-a2 * (128.0f * fl + 4096.0f));
        const float c2 = __expf(-8192.0f * a2);

        float t = fl * sstep;
        const float dt = 64.0f * sstep;

        float m0 = 0.f, m1 = 0.f, m2 = 0.f, m3 = 0.f, m4 = 0.f;
        #pragma unroll 4
        for (int i = lane; i < T; i += 64) {
            const float kv  = e1 + e2;
            const float u   = t * t;
            const float u2  = u * u;
            const float kvu2 = kv * u2;
            m0 += kv;
            m1 = fmaf(kv,   u,  m1);
            m2 += kvu2;
            m3 = fmaf(kvu2, u,  m3);
            m4 = fmaf(kvu2, u2, m4);
            e1 *= h1; h1 *= c1;
            e2 *= h2; h2 *= c2;
            t  += dt;
        }

        // wave-wide butterfly reduction (64 lanes)
        for (int off = 1; off < 64; off <<= 1) {
            m0 += __shfl_xor(m0, off);
            m1 += __shfl_xor(m1, off);
            m2 += __shfl_xor(m2, off);
            m3 += __shfl_xor(m3, off);
            m4 += __shfl_xor(m4, off);
        }

        if (lane == 0) {
            const float invT = 1.0f / (float)T;
            // endpoint trapezoid corrections: w[0]=w[T-1]=0.5/T, others 1/T
            const float kv0 = zf + zc;                                   // t=0
            const float kv1 = zf * __expf(-bA) + zc * __expf(-bE);       // t=1
            // moments -> Legendre projections (even l)
            const float r0 = m0;
            const float r2 = 1.5f * m1 - 0.5f * m0;
            const float r4 = 4.375f  * m2 - 3.75f    * m1 + 0.375f    * m0;
            const float r6 = 14.4375f* m3 - 19.6875f * m2 + 6.5625f   * m1 - 0.3125f   * m0;
            const float r8 = 50.2734375f*m4 - 93.84375f*m3 + 54.140625f*m2 - 9.84375f*m1 + 0.2734375f*m0;
            const float hc = 0.5f * invT;
            rho_s[w * 5 + 0] = r0 * invT - hc * (kv0 * 1.0f        + kv1);
            rho_s[w * 5 + 1] = r2 * invT - hc * (kv0 * -0.5f       + kv1);
            rho_s[w * 5 + 2] = r4 * invT - hc * (kv0 * 0.375f      + kv1);
            rho_s[w * 5 + 3] = r6 * invT - hc * (kv0 * -0.3125f    + kv1);
            rho_s[w * 5 + 4] = r8 * invT - hc * (kv0 * 0.2734375f  + kv1);
        }
    }

    __syncthreads();

    // ---------------- Phase 2a: eigen_values (N,B,F,K) ----------------
    if (tid < BB * FF * KK) {          // 405 threads
        const int bi = tid / (FF * KK);
        const int r  = tid % (FF * KK);
        const int f  = r / KK;
        const int k  = r % KK;
        int l, m, lidx;
        k_to_lm(k, l, m, lidx);
        outEig[(size_t)((n * BB + bi) * FF + f) * KK + k] = rho_s[(f * BB + bi) * 5 + lidx];
    }

    // ---------------- Phase 2b: Stensor (N,B,K) ----------------
    if (tid < BB * KK) {               // 135 threads
        const int bi = tid / KK;
        const int k  = tid % KK;
        int l, m, lidx;
        k_to_lm(k, l, m, lidx);
        float ssum = 0.0f;
        #pragma unroll
        for (int f = 0; f < FF; ++f) {
            ssum += weights[n * FF + f] * rho_s[(f * BB + bi) * 5 + lidx] * sh_s[f * KK + k];
        }
        outS[(size_t)(n * BB + bi) * KK + k] = ssum;
    }
}

extern "C" void kernel_launch(void* const* d_in, const int* in_sizes, int n_in,
                              void* d_out, int out_size, void* d_ws, size_t ws_size,
                              hipStream_t stream) {
    const float* directs = (const float*)d_in[0];   // (N,F,3)
    const float* weights = (const float*)d_in[1];   // (N,F)
    const float* shapes  = (const float*)d_in[2];   // (N,F,4)
    const int*   num_t   = (const int*)d_in[3];     // scalar

    const int N = in_sizes[0] / (FF * 3);

    float* outS   = (float*)d_out;                        // N*BB*KK
    float* outODF = outS + (size_t)N * BB * KK;           // N*FF*KK
    float* outEig = outODF + (size_t)N * FF * KK;         // N*BB*FF*KK

    fused_sim_kernel<<<N, TPB, 0, stream>>>(directs, weights, shapes, num_t,
                                            outS, outODF, outEig);
}

// Round 3
// 88.618 us; speedup vs baseline: 1.9901x; 1.7938x over previous
//
#include <hip/hip_runtime.h>
#include <math.h>

// Problem constants (from reference): LMAX=8, BVALS={1,2,3}
#define FF 3          // fibers per voxel
#define BB 3          // b-values
#define KK 45         // SH terms for even l in [0,8]: 1+5+9+13+17
#define TPB 256
#define NT 18         // Taylor terms k = 0..17 for I_l(a), |a| <= 3

// I_l(a) = int_0^1 exp(-a t^2) P_l(t) dt  (even l)
//        = sum_k d[l/2][k] * a^k,
// d[li][k] = (-1)^k / k! * prod_{j<l/2}(2k-2j) / prod_{j<=l/2}(2k+1+2j)
// (moment formula int_0^1 t^n P_l dt = n!/((n-l)!!(n+l+1)!!), n=2k)
struct Tab { float d[5][NT]; };

constexpr Tab make_tab() {
    Tab t{};
    for (int li = 0; li < 5; ++li) {
        const int l = 2 * li;
        double kfact = 1.0;
        for (int k = 0; k < NT; ++k) {
            if (k > 0) kfact *= (double)k;
            double c = 0.0;
            if (2 * k >= l) {
                double num = 1.0, den = 1.0;
                for (int j = 0; j < l / 2; ++j)  num *= (double)(2 * k - 2 * j);
                for (int j = 0; j <= l / 2; ++j) den *= (double)(2 * k + 1 + 2 * j);
                c = num / den;
            }
            t.d[li][k] = (float)(((k & 1) ? -1.0 : 1.0) * c / kfact);
        }
    }
    return t;
}

static constexpr Tab HOST_TAB = make_tab();
__constant__ Tab TAB = HOST_TAB;

// map k in [0,45) -> (l, m, lidx)
__device__ __forceinline__ void k_to_lm(int k, int& l, int& m, int& lidx) {
    int base;
    if (k < 1)       { l = 0; base = 0;  lidx = 0; }
    else if (k < 6)  { l = 2; base = 1;  lidx = 1; }
    else if (k < 15) { l = 4; base = 6;  lidx = 2; }
    else if (k < 28) { l = 6; base = 15; lidx = 3; }
    else             { l = 8; base = 28; lidx = 4; }
    m = k - base - l;
}

__device__ __forceinline__ void eval_I(float a, float I[5]) {
    #pragma unroll
    for (int li = 0; li < 5; ++li) {
        float acc = TAB.d[li][NT - 1];
        #pragma unroll
        for (int k = NT - 2; k >= 0; --k)
            acc = fmaf(acc, a, TAB.d[li][k]);
        I[li] = acc;
    }
}

__global__ __launch_bounds__(TPB) void fused_sim_kernel(
    const float* __restrict__ directs,   // (N,F,3)
    const float* __restrict__ weights,   // (N,F)
    const float* __restrict__ shapes,    // (N,F,4): D_a, D_epar, D_eperp, z
    const int*   __restrict__ num_t_p,   // scalar
    float* __restrict__ outS,            // (N,B,K)
    float* __restrict__ outODF,          // (N,F,K)
    float* __restrict__ outEig)          // (N,B,F,K)
{
    const int n   = blockIdx.x;
    const int tid = threadIdx.x;

    __shared__ float rho_s[FF * BB * 5];  // [f*3+b][lidx]
    __shared__ float sh_s[FF * KK];       // ODF basis per fiber

    // ---------------- Phase 1a: SH basis (threads 0..134, waves 0-2) ----------------
    if (tid < FF * KK) {
        const int f = tid / KK;
        const int k = tid % KK;
        const float dx = directs[(n * FF + f) * 3 + 0];
        const float dy = directs[(n * FF + f) * 3 + 1];
        const float dz = directs[(n * FF + f) * 3 + 2];
        const float inv = 1.0f / sqrtf(dx * dx + dy * dy + dz * dz);
        const float x = dx * inv, y = dy * inv, z = dz * inv;
        float s2 = 1.0f - z * z;
        s2 = fminf(fmaxf(s2, 0.0f), 1.0f);
        const float s = sqrtf(s2);

        // cos(phi), sin(phi): phi = atan2(y, x)
        const float rxy2 = x * x + y * y;
        float cphi = 1.0f, sphi = 0.0f;
        if (rxy2 > 0.0f) {
            const float ir = 1.0f / sqrtf(rxy2);
            cphi = x * ir;
            sphi = y * ir;
        }

        int l, m, lidx;
        k_to_lm(k, l, m, lidx);
        const int ma = (m < 0) ? -m : m;

        // cos(ma*phi), sin(ma*phi) via complex-mul recurrence
        float cm = 1.0f, sm = 0.0f;
        for (int mm = 0; mm < ma; ++mm) {
            const float cn = cm * cphi - sm * sphi;
            const float sn = sm * cphi + cm * sphi;
            cm = cn; sm = sn;
        }

        // associated Legendre P(l, ma) at z (Condon-Shortley)
        float pmm = 1.0f;
        for (int mm = 1; mm <= ma; ++mm)
            pmm *= -(float)(2 * mm - 1) * s;
        float P;
        if (l == ma) {
            P = pmm;
        } else {
            float pa = pmm;                              // P(ma,ma)
            float pb = (float)(2 * ma + 1) * z * pa;     // P(ma+1,ma)
            for (int ll = ma + 2; ll <= l; ++ll) {
                float pn = ((float)(2 * ll - 1) * z * pb - (float)(ll + ma - 1) * pa)
                           / (float)(ll - ma);
                pa = pb; pb = pn;
            }
            P = pb;
        }

        // normalization: sqrt((2l+1)/(4pi) / prod_{i=l-ma+1..l+ma} i)
        float prod = 1.0f;
        for (int i = l - ma + 1; i <= l + ma; ++i) prod *= (float)i;
        const float nrm = sqrtf((float)(2 * l + 1) * 0.079577471545947668f / prod);

        float val;
        if (m < 0)       val = 1.4142135623730951f * nrm * sm * P;
        else if (m == 0) val = nrm * P;
        else             val = 1.4142135623730951f * nrm * cm * P;

        sh_s[f * KK + k] = val;
        outODF[(size_t)(n * FF + f) * KK + k] = val;
    }

    // ---------------- Phase 1b: rho via analytic integral (wave 3, lanes 0-8) ----------------
    if (tid >= 192 && tid < 192 + FF * BB) {
        const int w  = tid - 192;
        const int f  = w / BB;
        const int bi = w % BB;
        const float bval = (float)(bi + 1);              // BVALS = {1,2,3}

        const float D_a     = shapes[(n * FF + f) * 4 + 0];
        const float D_epar  = shapes[(n * FF + f) * 4 + 1];
        const float D_eperp = shapes[(n * FF + f) * 4 + 2];
        const float zf      = shapes[(n * FF + f) * 4 + 3];

        const float bA = bval * D_a;
        const float bE = bval * (D_epar - D_eperp);
        const float zc = (1.0f - zf) * __expf(-bval * D_eperp);

        const float T     = (float)num_t_p[0];
        const float h     = 1.0f / (T - 1.0f);
        const float scale = (T - 1.0f) / T;   // reference weighs by 1/T, not 1/(T-1)
        const float h212  = h * h * (1.0f / 12.0f);

        float IA[5], IE[5];
        eval_I(bA, IA);
        eval_I(bE, IE);
        const float eA = __expf(-bA);
        const float eE = __expf(-bE);

        #pragma unroll
        for (int li = 0; li < 5; ++li) {
            const int   l   = 2 * li;
            const float pl1 = 0.5f * (float)(l * (l + 1));   // P_l'(1)
            // trapezoid(h) = exact + (h^2/12) * f'(1)   (f'(0)=0 for even l)
            const float QA = IA[li] + h212 * eA * (pl1 - 2.0f * bA);
            const float QE = IE[li] + h212 * eE * (pl1 - 2.0f * bE);
            rho_s[w * 5 + li] = scale * (zf * QA + zc * QE);
        }
    }

    __syncthreads();

    // ---------------- Phase 2a: eigen_values (N,B,F,K) ----------------
    for (int idx = tid; idx < BB * FF * KK; idx += TPB) {   // 405 elems
        const int bi = idx / (FF * KK);
        const int r  = idx % (FF * KK);
        const int f  = r / KK;
        const int k  = r % KK;
        int l, m, lidx;
        k_to_lm(k, l, m, lidx);
        outEig[(size_t)((n * BB + bi) * FF + f) * KK + k] = rho_s[(f * BB + bi) * 5 + lidx];
    }

    // ---------------- Phase 2b: Stensor (N,B,K) ----------------
    if (tid < BB * KK) {               // 135 threads
        const int bi = tid / KK;
        const int k  = tid % KK;
        int l, m, lidx;
        k_to_lm(k, l, m, lidx);
        float ssum = 0.0f;
        #pragma unroll
        for (int f = 0; f < FF; ++f) {
            ssum += weights[n * FF + f] * rho_s[(f * BB + bi) * 5 + lidx] * sh_s[f * KK + k];
        }
        outS[(size_t)(n * BB + bi) * KK + k] = ssum;
    }
}

extern "C" void kernel_launch(void* const* d_in, const int* in_sizes, int n_in,
                              void* d_out, int out_size, void* d_ws, size_t ws_size,
                              hipStream_t stream) {
    const float* directs = (const float*)d_in[0];   // (N,F,3)
    const float* weights = (const float*)d_in[1];   // (N,F)
    const float* shapes  = (const float*)d_in[2];   // (N,F,4)
    const int*   num_t   = (const int*)d_in[3];     // scalar

    const int N = in_sizes[0] / (FF * 3);

    float* outS   = (float*)d_out;                        // N*BB*KK
    float* outODF = outS + (size_t)N * BB * KK;           // N*FF*KK
    float* outEig = outODF + (size_t)N * FF * KK;         // N*BB*FF*KK

    fused_sim_kernel<<<N, TPB, 0, stream>>>(directs, weights, shapes, num_t,
                                            outS, outODF, outEig);
}

// Round 4
// 75.343 us; speedup vs baseline: 2.3408x; 1.1762x over previous
//
#include <hip/hip_runtime.h>
#include <math.h>

// Problem constants (from reference): LMAX=8, BVALS={1,2,3}
#define FF 3          // fibers per voxel
#define BB 3          // b-values
#define KK 45         // SH terms for even l in [0,8]: 1+5+9+13+17
#define VOX 4         // voxels per block
#define TPB 256
#define NT 18         // Taylor terms k = 0..17 for I_l(a), |a| <= 3
#define NFIB (VOX*FF)         // 12 fiber tasks / block
#define NRHO (VOX*FF*BB)      // 36 rho tasks / block

// ---------------- constexpr helpers ----------------
constexpr double csqrt(double x) {
    double g = x > 1.0 ? x : 1.0;
    for (int i = 0; i < 64; ++i) g = 0.5 * (g + x / g);
    return g;
}

// I_l(a) = int_0^1 exp(-a t^2) P_l(t) dt  (even l) = sum_k d[l/2][k] a^k
struct Tab { float d[5][NT]; };
constexpr Tab make_tab() {
    Tab t{};
    for (int li = 0; li < 5; ++li) {
        const int l = 2 * li;
        double kfact = 1.0;
        for (int k = 0; k < NT; ++k) {
            if (k > 0) kfact *= (double)k;
            double c = 0.0;
            if (2 * k >= l) {
                double num = 1.0, den = 1.0;
                for (int j = 0; j < l / 2; ++j)  num *= (double)(2 * k - 2 * j);
                for (int j = 0; j <= l / 2; ++j) den *= (double)(2 * k + 1 + 2 * j);
                c = num / den;
            }
            t.d[li][k] = (float)(((k & 1) ? -1.0 : 1.0) * c / kfact);
        }
    }
    return t;
}
static constexpr Tab HOST_TAB = make_tab();
__constant__ Tab TAB = HOST_TAB;

// per-k tables: k in [0,45) -> lidx=l/2, ma=|m|, neg=(m<0), nrm (incl sqrt2)
struct KTab {
    float nrm[KK];
    unsigned char lidx[KK];
    unsigned char ma[KK];
    unsigned char neg[KK];
};
constexpr KTab make_ktab() {
    KTab t{};
    int k = 0;
    for (int l = 0; l <= 8; l += 2) {
        for (int m = -l; m <= l; ++m, ++k) {
            const int ma = m < 0 ? -m : m;
            double prod = 1.0;
            for (int i = l - ma + 1; i <= l + ma; ++i) prod *= (double)i;
            double nrm = csqrt((double)(2 * l + 1) * 0.07957747154594767 / prod);
            if (m != 0) nrm *= csqrt(2.0);
            t.nrm[k]  = (float)nrm;
            t.lidx[k] = (unsigned char)(l / 2);
            t.ma[k]   = (unsigned char)ma;
            t.neg[k]  = (unsigned char)(m < 0 ? 1 : 0);
        }
    }
    return t;
}
static constexpr KTab HOST_KT = make_ktab();
__constant__ KTab KT = HOST_KT;

__device__ __forceinline__ void eval_I(float a, float I[5]) {
    #pragma unroll
    for (int li = 0; li < 5; ++li) {
        float acc = TAB.d[li][NT - 1];
        #pragma unroll
        for (int k = NT - 2; k >= 0; --k)
            acc = fmaf(acc, a, TAB.d[li][k]);
        I[li] = acc;
    }
}

__global__ __launch_bounds__(TPB) void fused_sim_kernel(
    const float* __restrict__ directs,   // (N,F,3)
    const float* __restrict__ weights,   // (N,F)
    const float* __restrict__ shapes,    // (N,F,4): D_a, D_epar, D_eperp, z
    const int*   __restrict__ num_t_p,   // scalar
    float* __restrict__ outS,            // (N,B,K)
    float* __restrict__ outODF,          // (N,F,K)
    float* __restrict__ outEig,          // (N,B,F,K)
    int N)
{
    const int n0  = blockIdx.x * VOX;
    const int tid = threadIdx.x;

    // P index within a fiber: lidx*lidx + ma  (offsets 0,1,4,9,16 -> 25 total)
    __shared__ float P_s[NFIB][25];
    __shared__ float cm_s[NFIB][9];
    __shared__ float sm_s[NFIB][9];
    __shared__ float rho_s[NRHO][5];
    __shared__ float sh_s[VOX * FF * KK];   // 540
    __shared__ float w_s[NFIB];

    // ---- Stage 1a (wave 0, lanes 0..11): per-fiber Legendre + trig + weight ----
    if (tid < NFIB) {
        const int v = tid / FF;
        const int f = tid % FF;
        const int n = n0 + v;
        if (n < N) {
            const float dx = directs[(n * FF + f) * 3 + 0];
            const float dy = directs[(n * FF + f) * 3 + 1];
            const float dz = directs[(n * FF + f) * 3 + 2];
            const float inv = 1.0f / sqrtf(dx * dx + dy * dy + dz * dz);
            const float x = dx * inv, y = dy * inv, z = dz * inv;
            float s2 = 1.0f - z * z;
            s2 = fminf(fmaxf(s2, 0.0f), 1.0f);
            const float s = sqrtf(s2);

            const float rxy2 = x * x + y * y;
            float cphi = 1.0f, sphi = 0.0f;
            if (rxy2 > 0.0f) {
                const float ir = 1.0f / sqrtf(rxy2);
                cphi = x * ir;
                sphi = y * ir;
            }

            // cos(m phi), sin(m phi), m = 0..8
            float cm = 1.0f, sm = 0.0f;
            #pragma unroll
            for (int m = 0; m <= 8; ++m) {
                cm_s[tid][m] = cm;
                sm_s[tid][m] = sm;
                const float cn = cm * cphi - sm * sphi;
                const float sn = sm * cphi + cm * sphi;
                cm = cn; sm = sn;
            }

            // associated Legendre P(l, ma) for even l in [0,8], ma <= l
            float pmm = 1.0f;   // P(ma,ma)
            #pragma unroll
            for (int ma = 0; ma <= 8; ++ma) {
                if (ma > 0) pmm *= -(float)(2 * ma - 1) * s;
                if ((ma & 1) == 0)
                    P_s[tid][(ma / 2) * (ma / 2) + ma] = pmm;
                float pa = pmm;
                float pb = (float)(2 * ma + 1) * z * pa;   // P(ma+1,ma)
                if (ma + 1 <= 8 && ((ma + 1) & 1) == 0)
                    P_s[tid][((ma + 1) / 2) * ((ma + 1) / 2) + ma] = pb;
                #pragma unroll
                for (int ll = ma + 2; ll <= 8; ++ll) {
                    const float invd = 1.0f / (float)(ll - ma);   // const after unroll
                    const float pn = ((float)(2 * ll - 1) * z * pb
                                      - (float)(ll + ma - 1) * pa) * invd;
                    pa = pb; pb = pn;
                    if ((ll & 1) == 0)
                        P_s[tid][(ll / 2) * (ll / 2) + ma] = pn;
                }
            }

            w_s[tid] = weights[n * FF + f];
        }
    }

    // ---- Stage 1b (wave 1, lanes 0..35): rho via analytic integral ----
    if (tid >= 64 && tid < 64 + NRHO) {
        const int w  = tid - 64;          // (v*FF + f)*BB + bi
        const int fi = w / BB;            // v*FF + f
        const int bi = w % BB;
        const int n  = n0 + fi / FF;
        const int f  = fi % FF;
        if (n < N) {
            const float bval = (float)(bi + 1);              // BVALS = {1,2,3}

            const float D_a     = shapes[(n * FF + f) * 4 + 0];
            const float D_epar  = shapes[(n * FF + f) * 4 + 1];
            const float D_eperp = shapes[(n * FF + f) * 4 + 2];
            const float zf      = shapes[(n * FF + f) * 4 + 3];

            const float bA = bval * D_a;
            const float bE = bval * (D_epar - D_eperp);
            const float zc = (1.0f - zf) * __expf(-bval * D_eperp);

            const float T     = (float)num_t_p[0];
            const float h     = 1.0f / (T - 1.0f);
            const float scale = (T - 1.0f) / T;   // ref weighs by 1/T, not 1/(T-1)
            const float h212  = h * h * (1.0f / 12.0f);

            float IA[5], IE[5];
            eval_I(bA, IA);
            eval_I(bE, IE);
            const float eA = __expf(-bA);
            const float eE = __expf(-bE);

            #pragma unroll
            for (int li = 0; li < 5; ++li) {
                const int   l   = 2 * li;
                const float pl1 = 0.5f * (float)(l * (l + 1));   // P_l'(1)
                const float QA = IA[li] + h212 * eA * (pl1 - 2.0f * bA);
                const float QE = IE[li] + h212 * eE * (pl1 - 2.0f * bE);
                rho_s[w][li] = scale * (zf * QA + zc * QE);
            }
        }
    }

    __syncthreads();

    // ---- Stage 2a: SH values -> LDS + outODF (VOX*FF*KK = 540 elems) ----
    #pragma unroll
    for (int idx = tid; idx < VOX * FF * KK; idx += TPB) {
        const int v = idx / (FF * KK);
        const int r = idx % (FF * KK);      // f*KK + k
        const int k = r % KK;
        const int fi = v * FF + r / KK;
        const int n = n0 + v;
        const int lidx = KT.lidx[k];
        const int ma   = KT.ma[k];
        const float tr = KT.neg[k] ? sm_s[fi][ma] : cm_s[fi][ma];
        const float val = KT.nrm[k] * tr * P_s[fi][lidx * lidx + ma];
        sh_s[v * (FF * KK) + r] = val;
        if (n < N) outODF[(size_t)n * (FF * KK) + r] = val;
    }

    __syncthreads();

    // ---- Stage 2b: outEig (VOX*405) ----
    for (int idx = tid; idx < VOX * BB * FF * KK; idx += TPB) {
        const int v = idx / (BB * FF * KK);
        const int r = idx % (BB * FF * KK); // bi*135 + f*45 + k
        const int n = n0 + v;
        const int bi = r / (FF * KK);
        const int rr = r % (FF * KK);
        const int f  = rr / KK;
        const int k  = rr % KK;
        if (n < N)
            outEig[(size_t)n * (BB * FF * KK) + r] =
                rho_s[(v * FF + f) * BB + bi][KT.lidx[k]];
    }

    // ---- Stage 2c: outS (VOX*135) ----
    for (int idx = tid; idx < VOX * BB * KK; idx += TPB) {
        const int v = idx / (BB * KK);
        const int r = idx % (BB * KK);      // bi*45 + k
        const int n = n0 + v;
        const int bi = r / KK;
        const int k  = r % KK;
        const int lidx = KT.lidx[k];
        float ssum = 0.0f;
        #pragma unroll
        for (int f = 0; f < FF; ++f) {
            const int fi = v * FF + f;
            ssum = fmaf(w_s[fi] * rho_s[fi * BB + bi][lidx],
                        sh_s[fi * KK + k], ssum);
        }
        if (n < N) outS[(size_t)n * (BB * KK) + r] = ssum;
    }
}

extern "C" void kernel_launch(void* const* d_in, const int* in_sizes, int n_in,
                              void* d_out, int out_size, void* d_ws, size_t ws_size,
                              hipStream_t stream) {
    const float* directs = (const float*)d_in[0];   // (N,F,3)
    const float* weights = (const float*)d_in[1];   // (N,F)
    const float* shapes  = (const float*)d_in[2];   // (N,F,4)
    const int*   num_t   = (const int*)d_in[3];     // scalar

    const int N = in_sizes[0] / (FF * 3);

    float* outS   = (float*)d_out;                        // N*BB*KK
    float* outODF = outS + (size_t)N * BB * KK;           // N*FF*KK
    float* outEig = outODF + (size_t)N * FF * KK;         // N*BB*FF*KK

    const int blocks = (N + VOX - 1) / VOX;
    fused_sim_kernel<<<blocks, TPB, 0, stream>>>(directs, weights, shapes, num_t,
                                                 outS, outODF, outEig, N);
}

// Round 5
// 73.278 us; speedup vs baseline: 2.4068x; 1.0282x over previous
//
#include <hip/hip_runtime.h>
#include <math.h>

// Problem constants (from reference): LMAX=8, BVALS={1,2,3}
#define FF 3          // fibers per voxel
#define BB 3          // b-values
#define KK 45         // SH terms for even l in [0,8]
#define VOX 8         // voxels per block
#define TPB 256
#define NT 18         // Taylor terms for I_l(a), |a| <= 3
#define NFIB (VOX*FF)         // 24 fiber tasks / block
#define NRHO (VOX*FF*BB)      // 72 rho tasks / block

// ---------------- constexpr helpers ----------------
constexpr double csqrt(double x) {
    double g = x > 1.0 ? x : 1.0;
    for (int i = 0; i < 64; ++i) g = 0.5 * (g + x / g);
    return g;
}

// I_l(a) = int_0^1 exp(-a t^2) P_l(t) dt  (even l) = sum_k d[l/2][k] a^k
struct Tab { float d[5][NT]; };
constexpr Tab make_tab() {
    Tab t{};
    for (int li = 0; li < 5; ++li) {
        const int l = 2 * li;
        double kfact = 1.0;
        for (int k = 0; k < NT; ++k) {
            if (k > 0) kfact *= (double)k;
            double c = 0.0;
            if (2 * k >= l) {
                double num = 1.0, den = 1.0;
                for (int j = 0; j < l / 2; ++j)  num *= (double)(2 * k - 2 * j);
                for (int j = 0; j <= l / 2; ++j) den *= (double)(2 * k + 1 + 2 * j);
                c = num / den;
            }
            t.d[li][k] = (float)(((k & 1) ? -1.0 : 1.0) * c / kfact);
        }
    }
    return t;
}
static constexpr Tab HOST_TAB = make_tab();
__constant__ Tab TAB = HOST_TAB;

// per-k tables
struct KTab {
    float nrm[KK];
    unsigned char lidx[KK];
    unsigned char ma[KK];
    unsigned char neg[KK];
};
constexpr KTab make_ktab() {
    KTab t{};
    int k = 0;
    for (int l = 0; l <= 8; l += 2) {
        for (int m = -l; m <= l; ++m, ++k) {
            const int ma = m < 0 ? -m : m;
            double prod = 1.0;
            for (int i = l - ma + 1; i <= l + ma; ++i) prod *= (double)i;
            double nrm = csqrt((double)(2 * l + 1) * 0.07957747154594767 / prod);
            if (m != 0) nrm *= csqrt(2.0);
            t.nrm[k]  = (float)nrm;
            t.lidx[k] = (unsigned char)(l / 2);
            t.ma[k]   = (unsigned char)ma;
            t.neg[k]  = (unsigned char)(m < 0 ? 1 : 0);
        }
    }
    return t;
}
static constexpr KTab HOST_KT = make_ktab();
__constant__ KTab KT = HOST_KT;

__device__ __forceinline__ void eval_I(float a, float I[5]) {
    #pragma unroll
    for (int li = 0; li < 5; ++li) {
        float acc = TAB.d[li][NT - 1];
        #pragma unroll
        for (int k = NT - 2; k >= 0; --k)
            acc = fmaf(acc, a, TAB.d[li][k]);
        I[li] = acc;
    }
}

__global__ __launch_bounds__(TPB) void fused_sim_kernel(
    const float* __restrict__ directs,   // (N,F,3)
    const float* __restrict__ weights,   // (N,F)
    const float* __restrict__ shapes,    // (N,F,4): D_a, D_epar, D_eperp, z
    const int*   __restrict__ num_t_p,   // scalar
    float* __restrict__ outS,            // (N,B,K)
    float* __restrict__ outODF,          // (N,F,K)
    float* __restrict__ outEig,          // (N,B,F,K)
    int N)
{
    const int n0  = blockIdx.x * VOX;
    const int tid = threadIdx.x;
    const bool full = (n0 + VOX <= N);

    __shared__ float P_s[NFIB][25];      // lidx*lidx + ma
    __shared__ float cm_s[NFIB][9];
    __shared__ float sm_s[NFIB][9];
    __shared__ float rho_s[NRHO][5];
    __shared__ float sh_s[VOX * FF * KK];   // 1080
    __shared__ float w_s[NFIB];

    // ---- Stage 1a (wave 0, lanes 0..23): per-fiber Legendre + trig + weight ----
    if (tid < NFIB) {
        const int v = tid / FF;
        const int f = tid % FF;
        const int n = n0 + v;
        if (n < N) {
            const float dx = directs[(n * FF + f) * 3 + 0];
            const float dy = directs[(n * FF + f) * 3 + 1];
            const float dz = directs[(n * FF + f) * 3 + 2];
            const float inv = 1.0f / sqrtf(dx * dx + dy * dy + dz * dz);
            const float x = dx * inv, y = dy * inv, z = dz * inv;
            float s2 = 1.0f - z * z;
            s2 = fminf(fmaxf(s2, 0.0f), 1.0f);
            const float s = sqrtf(s2);

            const float rxy2 = x * x + y * y;
            float cphi = 1.0f, sphi = 0.0f;
            if (rxy2 > 0.0f) {
                const float ir = 1.0f / sqrtf(rxy2);
                cphi = x * ir;
                sphi = y * ir;
            }

            float cm = 1.0f, sm = 0.0f;
            #pragma unroll
            for (int m = 0; m <= 8; ++m) {
                cm_s[tid][m] = cm;
                sm_s[tid][m] = sm;
                const float cn = cm * cphi - sm * sphi;
                const float sn = sm * cphi + cm * sphi;
                cm = cn; sm = sn;
            }

            float pmm = 1.0f;   // P(ma,ma)
            #pragma unroll
            for (int ma = 0; ma <= 8; ++ma) {
                if (ma > 0) pmm *= -(float)(2 * ma - 1) * s;
                if ((ma & 1) == 0)
                    P_s[tid][(ma / 2) * (ma / 2) + ma] = pmm;
                float pa = pmm;
                float pb = (float)(2 * ma + 1) * z * pa;   // P(ma+1,ma)
                if (ma + 1 <= 8 && ((ma + 1) & 1) == 0)
                    P_s[tid][((ma + 1) / 2) * ((ma + 1) / 2) + ma] = pb;
                #pragma unroll
                for (int ll = ma + 2; ll <= 8; ++ll) {
                    const float invd = 1.0f / (float)(ll - ma);
                    const float pn = ((float)(2 * ll - 1) * z * pb
                                      - (float)(ll + ma - 1) * pa) * invd;
                    pa = pb; pb = pn;
                    if ((ll & 1) == 0)
                        P_s[tid][(ll / 2) * (ll / 2) + ma] = pn;
                }
            }

            w_s[tid] = weights[n * FF + f];
        }
    }

    // ---- Stage 1b (waves 1-2, tids 64..135): rho via analytic integral ----
    if (tid >= 64 && tid < 64 + NRHO) {
        const int w  = tid - 64;          // (v*FF + f)*BB + bi
        const int fi = w / BB;
        const int bi = w % BB;
        const int n  = n0 + fi / FF;
        const int f  = fi % FF;
        if (n < N) {
            const float bval = (float)(bi + 1);              // BVALS = {1,2,3}

            const float D_a     = shapes[(n * FF + f) * 4 + 0];
            const float D_epar  = shapes[(n * FF + f) * 4 + 1];
            const float D_eperp = shapes[(n * FF + f) * 4 + 2];
            const float zf      = shapes[(n * FF + f) * 4 + 3];

            const float bA = bval * D_a;
            const float bE = bval * (D_epar - D_eperp);
            const float zc = (1.0f - zf) * __expf(-bval * D_eperp);

            const float T     = (float)num_t_p[0];
            const float h     = 1.0f / (T - 1.0f);
            const float scale = (T - 1.0f) / T;
            const float h212  = h * h * (1.0f / 12.0f);

            float IA[5], IE[5];
            eval_I(bA, IA);
            eval_I(bE, IE);
            const float eA = __expf(-bA);
            const float eE = __expf(-bE);

            #pragma unroll
            for (int li = 0; li < 5; ++li) {
                const int   l   = 2 * li;
                const float pl1 = 0.5f * (float)(l * (l + 1));
                const float QA = IA[li] + h212 * eA * (pl1 - 2.0f * bA);
                const float QE = IE[li] + h212 * eE * (pl1 - 2.0f * bE);
                rho_s[w][li] = scale * (zf * QA + zc * QE);
            }
        }
    }

    __syncthreads();

    // ---- Stage 2a: sh values -> LDS + outODF (VOX*FF*KK = 1080 = 270 quads) ----
    {
        float4* dst = (float4*)(outODF + (size_t)n0 * (FF * KK));
        for (int q = tid; q < VOX * FF * KK / 4; q += TPB) {
            float4 out;
            float* oc = &out.x;
            #pragma unroll
            for (int j = 0; j < 4; ++j) {
                const int e  = 4 * q + j;
                const int fi = e / KK;
                const int k  = e % KK;
                const int lidx = KT.lidx[k];
                const int ma   = KT.ma[k];
                const float tr = KT.neg[k] ? sm_s[fi][ma] : cm_s[fi][ma];
                const float val = KT.nrm[k] * tr * P_s[fi][lidx * lidx + ma];
                sh_s[e] = val;
                oc[j] = val;
            }
            if (full) {
                dst[q] = out;
            } else {
                #pragma unroll
                for (int j = 0; j < 4; ++j) {
                    const int e = 4 * q + j;
                    if (n0 + e / (FF * KK) < N)
                        outODF[(size_t)n0 * (FF * KK) + e] = oc[j];
                }
            }
        }
    }

    __syncthreads();

    // ---- Stage 2b: outEig (VOX*405 = 3240 = 810 quads) ----
    {
        float4* dst = (float4*)(outEig + (size_t)n0 * (BB * FF * KK));
        for (int q = tid; q < VOX * BB * FF * KK / 4; q += TPB) {
            float4 out;
            float* oc = &out.x;
            #pragma unroll
            for (int j = 0; j < 4; ++j) {
                const int e  = 4 * q + j;
                const int v  = e / (BB * FF * KK);
                const int r  = e % (BB * FF * KK);  // bi*135 + f*45 + k
                const int bi = r / (FF * KK);
                const int f  = (r / KK) % FF;
                const int k  = r % KK;
                oc[j] = rho_s[(v * FF + f) * BB + bi][KT.lidx[k]];
            }
            if (full) {
                dst[q] = out;
            } else {
                #pragma unroll
                for (int j = 0; j < 4; ++j) {
                    const int e = 4 * q + j;
                    if (n0 + e / (BB * FF * KK) < N)
                        outEig[(size_t)n0 * (BB * FF * KK) + e] = oc[j];
                }
            }
        }
    }

    // ---- Stage 2c: outS (VOX*135 = 1080 = 270 quads) ----
    {
        float4* dst = (float4*)(outS + (size_t)n0 * (BB * KK));
        for (int q = tid; q < VOX * BB * KK / 4; q += TPB) {
            float4 out;
            float* oc = &out.x;
            #pragma unroll
            for (int j = 0; j < 4; ++j) {
                const int e  = 4 * q + j;
                const int v  = e / (BB * KK);
                const int r  = e % (BB * KK);       // bi*45 + k
                const int bi = r / KK;
                const int k  = r % KK;
                const int lidx = KT.lidx[k];
                float ssum = 0.0f;
                #pragma unroll
                for (int f = 0; f < FF; ++f) {
                    const int fi = v * FF + f;
                    ssum = fmaf(w_s[fi] * rho_s[fi * BB + bi][lidx],
                                sh_s[fi * KK + k], ssum);
                }
                oc[j] = ssum;
            }
            if (full) {
                dst[q] = out;
            } else {
                #pragma unroll
                for (int j = 0; j < 4; ++j) {
                    const int e = 4 * q + j;
                    if (n0 + e / (BB * KK) < N)
                        outS[(size_t)n0 * (BB * KK) + e] = oc[j];
                }
            }
        }
    }
}

extern "C" void kernel_launch(void* const* d_in, const int* in_sizes, int n_in,
                              void* d_out, int out_size, void* d_ws, size_t ws_size,
                              hipStream_t stream) {
    const float* directs = (const float*)d_in[0];   // (N,F,3)
    const float* weights = (const float*)d_in[1];   // (N,F)
    const float* shapes  = (const float*)d_in[2];   // (N,F,4)
    const int*   num_t   = (const int*)d_in[3];     // scalar

    const int N = in_sizes[0] / (FF * 3);

    float* outS   = (float*)d_out;                        // N*BB*KK
    float* outODF = outS + (size_t)N * BB * KK;           // N*FF*KK
    float* outEig = outODF + (size_t)N * FF * KK;         // N*BB*FF*KK

    const int blocks = (N + VOX - 1) / VOX;
    fused_sim_kernel<<<blocks, TPB, 0, stream>>>(directs, weights, shapes, num_t,
                                                 outS, outODF, outEig, N);
}